// Round 11
// baseline (1031.987 us; speedup 1.0000x reference)
//
#include <hip/hip_runtime.h>

#define N_NODES 500000
#define N_EDGES 2000000
#define F_IN 117
#define H 128
#define NLAYERS 3

#define SCAN_E 2048
#define NB_SCAN ((N_NODES + SCAN_E - 1) / SCAN_E)   // 245
#define NBUCKET ((N_NODES + 511) >> 9)              // 977 dst-buckets of 512 nodes
#define FILL_CHUNK 8192
#define NB_FILL ((N_EDGES + FILL_CHUNK - 1) / FILL_CHUNK)   // 245

typedef __attribute__((ext_vector_type(8))) short short8v;   // 8 bf16 (4 VGPR)
typedef __attribute__((ext_vector_type(4))) float f32x4;

__device__ __forceinline__ unsigned short f2bf(float x) {    // RNE fp32->bf16
    unsigned u = __builtin_bit_cast(unsigned, x);
    u += 0x7FFFu + ((u >> 16) & 1u);
    return (unsigned short)(u >> 16);
}
__device__ __forceinline__ float bf2f(unsigned short s) {
    unsigned u = ((unsigned)s) << 16;
    return __builtin_bit_cast(float, u);
}
// tanh(x) = 1 - 2/(exp(2x)+1): 1 exp2 + 1 rcp, NaN-free at both extremes.
__device__ __forceinline__ float fast_tanh(float x) {
    float e = __builtin_amdgcn_exp2f(x * 2.885390081777927f);   // exp(2x)
    return 1.0f - 2.0f * __builtin_amdgcn_rcpf(e + 1.0f);
}

// ---------------- W prep: fp32 W[K][128] -> bf16 MFMA B-fragment order ----------------
__global__ void prep_w_kernel(const float* __restrict__ Wself,
                              const float* __restrict__ Wneigh,
                              const float* __restrict__ Win,
                              short* __restrict__ Wfrag,     // [3][64][64][8]
                              short* __restrict__ WfragIn) { // [32][64][8]
    const int tid = blockIdx.x * 256 + threadIdx.x;
    const int total_cmb = NLAYERS * 64 * 64;                 // 12288 frags*lanes
    if (tid < total_cmb) {
        const int lane = tid & 63;
        const int fi   = (tid >> 6) & 63;
        const int l    = tid >> 12;
        const int ks = fi & 7, ct = (fi >> 3) & 3, wc = fi >> 5;
        const int c = wc * 64 + ct * 16 + (lane & 15);
        const int kbase = ks * 32 + (lane >> 4) * 8;
        short8v out;
        #pragma unroll
        for (int j = 0; j < 8; ++j) {
            int k = kbase + j;
            float v = (k < 128) ? Wself [(size_t)l * H * H + k * H + c]
                                : Wneigh[(size_t)l * H * H + (k - 128) * H + c];
            out[j] = (short)f2bf(v);
        }
        *(short8v*)(Wfrag + (size_t)tid * 8) = out;
    } else if (tid < total_cmb + 32 * 64) {
        const int t2 = tid - total_cmb;
        const int lane = t2 & 63;
        const int fi   = t2 >> 6;        // 0..31
        const int ks = fi & 3, ct = (fi >> 2) & 3, wc = fi >> 4;
        const int c = wc * 64 + ct * 16 + (lane & 15);
        const int kbase = ks * 32 + (lane >> 4) * 8;
        short8v out;
        #pragma unroll
        for (int j = 0; j < 8; ++j) {
            int k = kbase + j;
            out[j] = (k < F_IN) ? (short)f2bf(Win[(size_t)k * H + c]) : (short)0;
        }
        *(short8v*)(WfragIn + (size_t)t2 * 8) = out;
    }
}

// ---------------- proj: h = bf16(tanh(x @ W_in + b_in)), fp32 x read direct -----------
__global__ __launch_bounds__(512, 2) void proj_mfma(const short* __restrict__ WfragIn,
                                                    const float* __restrict__ bias,
                                                    const float* __restrict__ x,
                                                    unsigned short* __restrict__ hb) {
    const int wave = threadIdx.x >> 6;
    const int lane = threadIdx.x & 63;
    const int wc   = wave & 1;

    short8v Bf[4][4];
    #pragma unroll
    for (int ct = 0; ct < 4; ++ct)
        #pragma unroll
        for (int ks = 0; ks < 4; ++ks)
            Bf[ct][ks] = ((const short8v*)WfragIn)[(size_t)(((wc * 4 + ct) * 4 + ks) * 64 + lane)];

    float bs[4];
    #pragma unroll
    for (int ct = 0; ct < 4; ++ct) bs[ct] = bias[wc * 64 + ct * 16 + (lane & 15)];

    const int cbase = (lane >> 4) * 8;
    const int ntasks = (N_NODES / 16) * 2;   // 62500
    for (int task = blockIdx.x * 8 + wave; task < ntasks; task += gridDim.x * 8) {
        const int r0  = (task >> 1) * 16;
        const int row = r0 + (lane & 15);
        const float* xr = x + (size_t)row * F_IN;

        short8v Af[4];
        #pragma unroll
        for (int ks = 0; ks < 4; ++ks) {
            const int k0 = ks * 32 + cbase;
            short8v a;
            if (row == N_NODES - 1 && k0 + 7 >= F_IN) {   // rare: avoid OOB past x[]
                #pragma unroll
                for (int j = 0; j < 8; ++j) {
                    int k = k0 + j;
                    a[j] = (k < F_IN) ? (short)f2bf(xr[k]) : (short)0;
                }
            } else {
                #pragma unroll
                for (int j = 0; j < 8; ++j) a[j] = (short)f2bf(xr[k0 + j]);
            }
            Af[ks] = a;
        }

        f32x4 acc[4];
        #pragma unroll
        for (int ct = 0; ct < 4; ++ct) acc[ct] = (f32x4){0.f, 0.f, 0.f, 0.f};
        #pragma unroll
        for (int ks = 0; ks < 4; ++ks)
            #pragma unroll
            for (int ct = 0; ct < 4; ++ct)
                acc[ct] = __builtin_amdgcn_mfma_f32_16x16x32_bf16(Af[ks], Bf[ct][ks], acc[ct], 0, 0, 0);

        #pragma unroll
        for (int ct = 0; ct < 4; ++ct) {
            const int col = wc * 64 + ct * 16 + (lane & 15);
            #pragma unroll
            for (int q = 0; q < 4; ++q) {
                float v = fast_tanh(acc[ct][q] + bs[ct]);
                hb[(size_t)(r0 + (lane >> 4) * 4 + q) * H + col] = f2bf(v);
            }
        }
    }
}

// ---------------- CSR build ----------------
__global__ void zero_int_kernel(int* __restrict__ p, int n) {
    int i = blockIdx.x * blockDim.x + threadIdx.x;
    if (i < n) p[i] = 0;
}

__global__ void hist_kernel(const int* __restrict__ dst, int* __restrict__ cnt) {
    int e = blockIdx.x * blockDim.x + threadIdx.x;
    if (e < N_EDGES) atomicAdd(&cnt[dst[e]], 1);
}

__global__ __launch_bounds__(256) void scan_reduce_kernel(const int* __restrict__ cnt,
                                                          int* __restrict__ bsums) {
    __shared__ int s[256];
    const int base = blockIdx.x * SCAN_E;
    int sum = 0;
    for (int i = threadIdx.x; i < SCAN_E; i += 256) {
        int idx = base + i;
        sum += (idx < N_NODES) ? cnt[idx] : 0;
    }
    s[threadIdx.x] = sum;
    __syncthreads();
    for (int off = 128; off > 0; off >>= 1) {
        if (threadIdx.x < off) s[threadIdx.x] += s[threadIdx.x + off];
        __syncthreads();
    }
    if (threadIdx.x == 0) bsums[blockIdx.x] = s[0];
}

__global__ void scan_bsums_kernel(int* __restrict__ bsums) {   // 1 block, 256 threads
    __shared__ int s[256];
    const int tid = threadIdx.x;
    int v = (tid < NB_SCAN) ? bsums[tid] : 0;
    s[tid] = v;
    __syncthreads();
    for (int off = 1; off < 256; off <<= 1) {
        int add = (tid >= off) ? s[tid - off] : 0;
        __syncthreads();
        s[tid] += add;
        __syncthreads();
    }
    if (tid < NB_SCAN) bsums[tid] = s[tid] - v;   // exclusive
}

__global__ __launch_bounds__(256) void scan_final_kernel(const int* __restrict__ cnt,
                                                         const int* __restrict__ bsums,
                                                         int* __restrict__ start,
                                                         float* __restrict__ inv,
                                                         int* __restrict__ bcur) {
    __shared__ int tsum[256];
    const int tid = threadIdx.x;
    const int base = blockIdx.x * SCAN_E + tid * 8;
    int c[8];
    int s = 0;
    #pragma unroll
    for (int k = 0; k < 8; ++k) {
        int idx = base + k;
        c[k] = (idx < N_NODES) ? cnt[idx] : 0;
        s += c[k];
    }
    tsum[tid] = s;
    __syncthreads();
    for (int off = 1; off < 256; off <<= 1) {
        int add = (tid >= off) ? tsum[tid - off] : 0;
        __syncthreads();
        tsum[tid] += add;
        __syncthreads();
    }
    int off0 = bsums[blockIdx.x] + tsum[tid] - s;
    #pragma unroll
    for (int k = 0; k < 8; ++k) {
        int idx = base + k;
        if (idx < N_NODES) {
            start[idx] = off0;
            inv[idx]   = 1.0f / fmaxf((float)c[k], 1.0f);
            if ((idx & 511) == 0) bcur[idx >> 9] = off0;   // bucket write cursor
            off0 += c[k];
        }
    }
}

// Phase B: block-local LDS binning -> one global atomic per (block,bucket), dense writes.
__global__ __launch_bounds__(256) void bin_fill_kernel(const int* __restrict__ src,
                                                       const int* __restrict__ dst,
                                                       int* __restrict__ bcur,
                                                       int2* __restrict__ pairs) {
    __shared__ int2 ep[FILL_CHUNK];      // 64 KB edge stage
    __shared__ int  hist[NBUCKET];       // 3.9 KB: count -> base cursor
    const int t  = threadIdx.x;
    const int e0 = blockIdx.x * FILL_CHUNK;
    const int n  = min(FILL_CHUNK, N_EDGES - e0);

    for (int i = t; i < NBUCKET; i += 256) hist[i] = 0;
    __syncthreads();
    for (int i = t; i < n; i += 256) {
        int s = src[e0 + i], d = dst[e0 + i];
        ep[i] = make_int2(s, d);
        atomicAdd(&hist[d >> 9], 1);
    }
    __syncthreads();
    for (int i = t; i < NBUCKET; i += 256) {
        int c = hist[i];
        hist[i] = c ? atomicAdd(&bcur[i], c) : 0;   // reserve dense region
    }
    __syncthreads();
    for (int i = t; i < n; i += 256) {
        int2 p = ep[i];
        int pos = atomicAdd(&hist[p.y >> 9], 1);    // LDS cursor
        pairs[pos] = p;
    }
}

// Phase C: block = bucket; per-node cursors in LDS; srcs writes land in an 8KB window.
__global__ __launch_bounds__(256) void bucket_scatter_kernel(const int* __restrict__ start,
                                                             const int2* __restrict__ pairs,
                                                             int* __restrict__ srcs) {
    __shared__ int cur[512];
    const int b   = blockIdx.x;
    const int nb0 = b << 9;
    const int nend = min(nb0 + 512, N_NODES);
    const int t = threadIdx.x;
    for (int i = t; i < nend - nb0; i += 256) cur[i] = start[nb0 + i];
    __syncthreads();
    const int ebeg = start[nb0];
    const int eend = (nend < N_NODES) ? start[nend] : N_EDGES;
    for (int i = ebeg + t; i < eend; i += 256) {
        int2 p = pairs[i];
        int pos = atomicAdd(&cur[p.y - nb0], 1);    // LDS atomic
        srcs[pos] = p.x;
    }
}

// ---------------- gather: ns_bf[n] = bf16(mean nbr h_bf), 32 lanes/node, 8B loads ----
// Same traffic as 16-lane version (row = 32 lanes x 8B coalesced); 2x waves for TLP.
__global__ __launch_bounds__(256) void gather_kernel(const int* __restrict__ start,
                                                     const int* __restrict__ cnt,
                                                     const int* __restrict__ srcs,
                                                     const float* __restrict__ inv,
                                                     const unsigned short* __restrict__ hb,
                                                     unsigned short* __restrict__ nsb) {
    const int idx  = blockIdx.x * 256 + threadIdx.x;
    const int node = idx >> 5;
    if (node >= N_NODES) return;
    const int f = (idx & 31) * 4;
    const int st = start[node];
    const int c  = cnt[node];
    float a[4];
    #pragma unroll
    for (int i = 0; i < 4; ++i) a[i] = 0.f;
    int j = 0;
    for (; j + 4 <= c; j += 4) {           // 4 outstanding 8B loads
        const int s0 = srcs[st + j + 0];
        const int s1 = srcs[st + j + 1];
        const int s2 = srcs[st + j + 2];
        const int s3 = srcs[st + j + 3];
        const ushort4 v0 = *(const ushort4*)(hb + (size_t)s0 * H + f);
        const ushort4 v1 = *(const ushort4*)(hb + (size_t)s1 * H + f);
        const ushort4 v2 = *(const ushort4*)(hb + (size_t)s2 * H + f);
        const ushort4 v3 = *(const ushort4*)(hb + (size_t)s3 * H + f);
        a[0] += (bf2f(v0.x) + bf2f(v1.x)) + (bf2f(v2.x) + bf2f(v3.x));
        a[1] += (bf2f(v0.y) + bf2f(v1.y)) + (bf2f(v2.y) + bf2f(v3.y));
        a[2] += (bf2f(v0.z) + bf2f(v1.z)) + (bf2f(v2.z) + bf2f(v3.z));
        a[3] += (bf2f(v0.w) + bf2f(v1.w)) + (bf2f(v2.w) + bf2f(v3.w));
    }
    if (j + 2 <= c) {
        const int s0 = srcs[st + j + 0];
        const int s1 = srcs[st + j + 1];
        const ushort4 v0 = *(const ushort4*)(hb + (size_t)s0 * H + f);
        const ushort4 v1 = *(const ushort4*)(hb + (size_t)s1 * H + f);
        a[0] += bf2f(v0.x) + bf2f(v1.x);
        a[1] += bf2f(v0.y) + bf2f(v1.y);
        a[2] += bf2f(v0.z) + bf2f(v1.z);
        a[3] += bf2f(v0.w) + bf2f(v1.w);
        j += 2;
    }
    if (j < c) {
        const int s0 = srcs[st + j];
        const ushort4 v0 = *(const ushort4*)(hb + (size_t)s0 * H + f);
        a[0] += bf2f(v0.x); a[1] += bf2f(v0.y); a[2] += bf2f(v0.z); a[3] += bf2f(v0.w);
    }
    const float iv = inv[node];
    ushort4 o;
    o.x = f2bf(a[0] * iv); o.y = f2bf(a[1] * iv);
    o.z = f2bf(a[2] * iv); o.w = f2bf(a[3] * iv);
    *(ushort4*)(nsb + (size_t)node * H + f) = o;
}

// ---------------- combine: out = relu([h|ns] @ [Ws;Wn] + b), K=256 MFMA ---------------
// bf16 layers: direct scalar stores (measured ~4.8 TB/s effective, near-roof).
// fp32 last layer: wave-private LDS transpose -> float4 stores (was 2.7 TB/s scalar).
__global__ __launch_bounds__(512, 2) void combine_mfma(const short* __restrict__ Wfrag,
                                                       const float* __restrict__ bias,
                                                       const unsigned short* __restrict__ hb,
                                                       const unsigned short* __restrict__ nsb,
                                                       unsigned short* __restrict__ outb,
                                                       float* __restrict__ outf,
                                                       int last) {
    __shared__ __align__(16) float eplds[8][16 * 68];   // per-wave [16][68] f32 (fp32 path)
    const int wave = threadIdx.x >> 6;
    const int lane = threadIdx.x & 63;
    const int wc   = wave & 1;
    float* myl = &eplds[wave][0];

    short8v Bf[4][8];
    #pragma unroll
    for (int ct = 0; ct < 4; ++ct)
        #pragma unroll
        for (int ks = 0; ks < 8; ++ks)
            Bf[ct][ks] = ((const short8v*)Wfrag)[(size_t)(((wc * 4 + ct) * 8 + ks) * 64 + lane)];

    float bs[4];
    #pragma unroll
    for (int ct = 0; ct < 4; ++ct) bs[ct] = bias[wc * 64 + ct * 16 + (lane & 15)];

    const int ntasks = (N_NODES / 16) * 2;   // 62500
    for (int task = blockIdx.x * 8 + wave; task < ntasks; task += gridDim.x * 8) {
        const int r0 = (task >> 1) * 16;
        const unsigned short* arow = hb  + (size_t)(r0 + (lane & 15)) * H + (lane >> 4) * 8;
        const unsigned short* nrow = nsb + (size_t)(r0 + (lane & 15)) * H + (lane >> 4) * 8;
        short8v Af[8];
        #pragma unroll
        for (int ks = 0; ks < 4; ++ks) Af[ks]     = *(const short8v*)(arow + ks * 32);
        #pragma unroll
        for (int ks = 0; ks < 4; ++ks) Af[4 + ks] = *(const short8v*)(nrow + ks * 32);

        f32x4 acc[4];
        #pragma unroll
        for (int ct = 0; ct < 4; ++ct) acc[ct] = (f32x4){0.f, 0.f, 0.f, 0.f};
        #pragma unroll
        for (int ks = 0; ks < 8; ++ks)
            #pragma unroll
            for (int ct = 0; ct < 4; ++ct)
                acc[ct] = __builtin_amdgcn_mfma_f32_16x16x32_bf16(Af[ks], Bf[ct][ks], acc[ct], 0, 0, 0);

        if (!last) {
            #pragma unroll
            for (int ct = 0; ct < 4; ++ct) {
                const int col = wc * 64 + ct * 16 + (lane & 15);
                #pragma unroll
                for (int q = 0; q < 4; ++q) {
                    float v = fmaxf(acc[ct][q] + bs[ct], 0.f);
                    outb[(size_t)(r0 + (lane >> 4) * 4 + q) * H + col] = f2bf(v);
                }
            }
        } else {
            #pragma unroll
            for (int ct = 0; ct < 4; ++ct)
                #pragma unroll
                for (int q = 0; q < 4; ++q)
                    myl[((lane >> 4) * 4 + q) * 68 + ct * 16 + (lane & 15)] =
                        fmaxf(acc[ct][q] + bs[ct], 0.f);
            asm volatile("s_waitcnt lgkmcnt(0)" ::: "memory");
            __builtin_amdgcn_sched_barrier(0);
            #pragma unroll
            for (int i = 0; i < 4; ++i) {
                const int g = i * 64 + lane;               // 256 float4 in tile
                const int rw = g >> 4, seg = g & 15;
                float4 val = *(const float4*)(myl + rw * 68 + seg * 4);
                *(float4*)(outf + (size_t)(r0 + rw) * H + wc * 64 + seg * 4) = val;
            }
            asm volatile("" ::: "memory");                 // reads done before next overwrite
        }
    }
}

// ---------------- launch ----------------
extern "C" void kernel_launch(void* const* d_in, const int* in_sizes, int n_in,
                              void* d_out, int out_size, void* d_ws, size_t ws_size,
                              hipStream_t stream) {
    const float* x        = (const float*)d_in[0];
    const int*   edge_src = (const int*)d_in[1];
    const int*   edge_dst = (const int*)d_in[2];
    const float* W_in     = (const float*)d_in[3];
    const float* b_in     = (const float*)d_in[4];
    const float* W_self   = (const float*)d_in[5];
    const float* W_neigh  = (const float*)d_in[6];
    const float* b_layers = (const float*)d_in[7];

    // ws layout (~272.4 MB, all 16B-aligned)
    unsigned short* h0  = (unsigned short*)d_ws;               // 128 MB
    unsigned short* nsb = h0 + (size_t)N_NODES * H;            // 128 MB (pairs alias pre-gather)
    int*   cnt    = (int*)(nsb + (size_t)N_NODES * H);         // 2 MB
    int*   start  = cnt + N_NODES;                             // 2 MB
    float* inv    = (float*)(start + N_NODES);                 // 2 MB
    int*   srcs   = (int*)(inv + N_NODES);                     // 8 MB
    int*   bsums  = srcs + N_EDGES;                            // 1 KB
    short* Wfrag  = (short*)(bsums + 256);                     // 192 KB  [3][64][64][8]
    short* WfragIn = Wfrag + (size_t)NLAYERS * 64 * 64 * 8;    // 32 KB   [32][64][8]
    int*   bcur   = (int*)(WfragIn + 32 * 64 * 8);             // 4 KB (977 used)
    int2*  pairs  = (int2*)nsb;                                // 16 MB, dead before gather
    // h1 (bf16) lives in d_out's lower 128 MB until the final fp32 write
    unsigned short* h1 = (unsigned short*)d_out;

    prep_w_kernel<<<(NLAYERS * 64 * 64 + 32 * 64 + 255) / 256, 256, 0, stream>>>(
        W_self, W_neigh, W_in, Wfrag, WfragIn);

    // CSR build (edge_dst static): hist -> scan -> LDS-binned two-phase fill
    zero_int_kernel<<<(N_NODES + 255) / 256, 256, 0, stream>>>(cnt, N_NODES);
    hist_kernel<<<(N_EDGES + 255) / 256, 256, 0, stream>>>(edge_dst, cnt);
    scan_reduce_kernel<<<NB_SCAN, 256, 0, stream>>>(cnt, bsums);
    scan_bsums_kernel<<<1, 256, 0, stream>>>(bsums);
    scan_final_kernel<<<NB_SCAN, 256, 0, stream>>>(cnt, bsums, start, inv, bcur);
    bin_fill_kernel<<<NB_FILL, 256, 0, stream>>>(edge_src, edge_dst, bcur, pairs);
    bucket_scatter_kernel<<<NBUCKET, 256, 0, stream>>>(start, pairs, srcs);

    // input projection (MFMA, fused fp32->bf16 convert, fast-tanh epilogue)
    proj_mfma<<<1024, 512, 0, stream>>>(WfragIn, b_in, x, h0);

    const int gather_grid = (N_NODES * 32 + 255) / 256;
    // L0: h0 -> h1 ; L1: h1 -> h0 ; L2: h0 -> fp32 d_out
    gather_kernel<<<gather_grid, 256, 0, stream>>>(start, cnt, srcs, inv, h0, nsb);
    combine_mfma<<<1024, 512, 0, stream>>>(Wfrag + 0 * 64 * 64 * 8, b_layers + 0 * H,
                                           h0, nsb, h1, nullptr, 0);
    gather_kernel<<<gather_grid, 256, 0, stream>>>(start, cnt, srcs, inv, h1, nsb);
    combine_mfma<<<1024, 512, 0, stream>>>(Wfrag + 1 * 64 * 64 * 8, b_layers + 1 * H,
                                           h1, nsb, h0, nullptr, 0);
    gather_kernel<<<gather_grid, 256, 0, stream>>>(start, cnt, srcs, inv, h0, nsb);
    combine_mfma<<<1024, 512, 0, stream>>>(Wfrag + 2 * 64 * 64 * 8, b_layers + 2 * H,
                                           h0, nsb, nullptr, (float*)d_out, 1);
}

// Round 12
// 912.752 us; speedup vs baseline: 1.1306x; 1.1306x over previous
//
#include <hip/hip_runtime.h>

#define N_NODES 500000
#define N_EDGES 2000000
#define F_IN 117
#define H 128
#define NLAYERS 3

#define SCAN_E 2048
#define NB_SCAN ((N_NODES + SCAN_E - 1) / SCAN_E)   // 245
#define NBUCKET ((N_NODES + 511) >> 9)              // 977 dst-buckets of 512 nodes
#define FILL_CHUNK 8192
#define NB_FILL ((N_EDGES + FILL_CHUNK - 1) / FILL_CHUNK)   // 245

typedef __attribute__((ext_vector_type(8))) short short8v;            // 8 bf16 (4 VGPR)
typedef __attribute__((ext_vector_type(4))) float f32x4;
typedef float __attribute__((ext_vector_type(4), aligned(4))) f32x4u; // 4B-aligned vec load

__device__ __forceinline__ unsigned short f2bf(float x) {    // RNE fp32->bf16
    unsigned u = __builtin_bit_cast(unsigned, x);
    u += 0x7FFFu + ((u >> 16) & 1u);
    return (unsigned short)(u >> 16);
}
__device__ __forceinline__ float bf2f(unsigned short s) {
    unsigned u = ((unsigned)s) << 16;
    return __builtin_bit_cast(float, u);
}
// tanh(x) = 1 - 2/(exp(2x)+1): 1 exp2 + 1 rcp, NaN-free at both extremes.
__device__ __forceinline__ float fast_tanh(float x) {
    float e = __builtin_amdgcn_exp2f(x * 2.885390081777927f);   // exp(2x)
    return 1.0f - 2.0f * __builtin_amdgcn_rcpf(e + 1.0f);
}

// ---------------- W prep: fp32 W[K][128] -> bf16 MFMA B-fragment order ----------------
__global__ void prep_w_kernel(const float* __restrict__ Wself,
                              const float* __restrict__ Wneigh,
                              const float* __restrict__ Win,
                              short* __restrict__ Wfrag,     // [3][64][64][8]
                              short* __restrict__ WfragIn) { // [32][64][8]
    const int tid = blockIdx.x * 256 + threadIdx.x;
    const int total_cmb = NLAYERS * 64 * 64;                 // 12288 frags*lanes
    if (tid < total_cmb) {
        const int lane = tid & 63;
        const int fi   = (tid >> 6) & 63;
        const int l    = tid >> 12;
        const int ks = fi & 7, ct = (fi >> 3) & 3, wc = fi >> 5;
        const int c = wc * 64 + ct * 16 + (lane & 15);
        const int kbase = ks * 32 + (lane >> 4) * 8;
        short8v out;
        #pragma unroll
        for (int j = 0; j < 8; ++j) {
            int k = kbase + j;
            float v = (k < 128) ? Wself [(size_t)l * H * H + k * H + c]
                                : Wneigh[(size_t)l * H * H + (k - 128) * H + c];
            out[j] = (short)f2bf(v);
        }
        *(short8v*)(Wfrag + (size_t)tid * 8) = out;
    } else if (tid < total_cmb + 32 * 64) {
        const int t2 = tid - total_cmb;
        const int lane = t2 & 63;
        const int fi   = t2 >> 6;        // 0..31
        const int ks = fi & 3, ct = (fi >> 2) & 3, wc = fi >> 4;
        const int c = wc * 64 + ct * 16 + (lane & 15);
        const int kbase = ks * 32 + (lane >> 4) * 8;
        short8v out;
        #pragma unroll
        for (int j = 0; j < 8; ++j) {
            int k = kbase + j;
            out[j] = (k < F_IN) ? (short)f2bf(Win[(size_t)k * H + c]) : (short)0;
        }
        *(short8v*)(WfragIn + (size_t)t2 * 8) = out;
    }
}

// ---------------- proj: h = bf16(tanh(x @ W_in + b_in)), fp32 x read direct -----------
__global__ __launch_bounds__(512, 2) void proj_mfma(const short* __restrict__ WfragIn,
                                                    const float* __restrict__ bias,
                                                    const float* __restrict__ x,
                                                    unsigned short* __restrict__ hb) {
    const int wave = threadIdx.x >> 6;
    const int lane = threadIdx.x & 63;
    const int wc   = wave & 1;

    short8v Bf[4][4];
    #pragma unroll
    for (int ct = 0; ct < 4; ++ct)
        #pragma unroll
        for (int ks = 0; ks < 4; ++ks)
            Bf[ct][ks] = ((const short8v*)WfragIn)[(size_t)(((wc * 4 + ct) * 4 + ks) * 64 + lane)];

    float bs[4];
    #pragma unroll
    for (int ct = 0; ct < 4; ++ct) bs[ct] = bias[wc * 64 + ct * 16 + (lane & 15)];

    const int cbase = (lane >> 4) * 8;
    const int ntasks = (N_NODES / 16) * 2;   // 62500
    for (int task = blockIdx.x * 8 + wave; task < ntasks; task += gridDim.x * 8) {
        const int r0  = (task >> 1) * 16;
        const int row = r0 + (lane & 15);
        const float* xr = x + (size_t)row * F_IN;

        short8v Af[4];
        #pragma unroll
        for (int ks = 0; ks < 4; ++ks) {
            const int k0 = ks * 32 + cbase;
            short8v a;
            if (row == N_NODES - 1 && k0 + 7 >= F_IN) {   // rare: avoid OOB past x[]
                #pragma unroll
                for (int j = 0; j < 8; ++j) {
                    int k = k0 + j;
                    a[j] = (k < F_IN) ? (short)f2bf(xr[k]) : (short)0;
                }
            } else {                                       // cols>=117 hit zeroed B rows
                const f32x4u p0 = *(const f32x4u*)(xr + k0);
                const f32x4u p1 = *(const f32x4u*)(xr + k0 + 4);
                a[0] = (short)f2bf(p0[0]); a[1] = (short)f2bf(p0[1]);
                a[2] = (short)f2bf(p0[2]); a[3] = (short)f2bf(p0[3]);
                a[4] = (short)f2bf(p1[0]); a[5] = (short)f2bf(p1[1]);
                a[6] = (short)f2bf(p1[2]); a[7] = (short)f2bf(p1[3]);
            }
            Af[ks] = a;
        }

        f32x4 acc[4];
        #pragma unroll
        for (int ct = 0; ct < 4; ++ct) acc[ct] = (f32x4){0.f, 0.f, 0.f, 0.f};
        #pragma unroll
        for (int ks = 0; ks < 4; ++ks)
            #pragma unroll
            for (int ct = 0; ct < 4; ++ct)
                acc[ct] = __builtin_amdgcn_mfma_f32_16x16x32_bf16(Af[ks], Bf[ct][ks], acc[ct], 0, 0, 0);

        #pragma unroll
        for (int ct = 0; ct < 4; ++ct) {
            const int col = wc * 64 + ct * 16 + (lane & 15);
            #pragma unroll
            for (int q = 0; q < 4; ++q) {
                float v = fast_tanh(acc[ct][q] + bs[ct]);
                hb[(size_t)(r0 + (lane >> 4) * 4 + q) * H + col] = f2bf(v);
            }
        }
    }
}

// ---------------- CSR build ----------------
__global__ void zero_int_kernel(int* __restrict__ p, int n) {
    int i = blockIdx.x * blockDim.x + threadIdx.x;
    if (i < n) p[i] = 0;
}

__global__ void hist_kernel(const int* __restrict__ dst, int* __restrict__ cnt) {
    int e = blockIdx.x * blockDim.x + threadIdx.x;
    if (e < N_EDGES) atomicAdd(&cnt[dst[e]], 1);
}

__global__ __launch_bounds__(256) void scan_reduce_kernel(const int* __restrict__ cnt,
                                                          int* __restrict__ bsums) {
    __shared__ int s[256];
    const int base = blockIdx.x * SCAN_E;
    int sum = 0;
    for (int i = threadIdx.x; i < SCAN_E; i += 256) {
        int idx = base + i;
        sum += (idx < N_NODES) ? cnt[idx] : 0;
    }
    s[threadIdx.x] = sum;
    __syncthreads();
    for (int off = 128; off > 0; off >>= 1) {
        if (threadIdx.x < off) s[threadIdx.x] += s[threadIdx.x + off];
        __syncthreads();
    }
    if (threadIdx.x == 0) bsums[blockIdx.x] = s[0];
}

__global__ void scan_bsums_kernel(int* __restrict__ bsums) {   // 1 block, 256 threads
    __shared__ int s[256];
    const int tid = threadIdx.x;
    int v = (tid < NB_SCAN) ? bsums[tid] : 0;
    s[tid] = v;
    __syncthreads();
    for (int off = 1; off < 256; off <<= 1) {
        int add = (tid >= off) ? s[tid - off] : 0;
        __syncthreads();
        s[tid] += add;
        __syncthreads();
    }
    if (tid < NB_SCAN) bsums[tid] = s[tid] - v;   // exclusive
}

__global__ __launch_bounds__(256) void scan_final_kernel(const int* __restrict__ cnt,
                                                         const int* __restrict__ bsums,
                                                         int* __restrict__ start,
                                                         float* __restrict__ inv,
                                                         int* __restrict__ bcur) {
    __shared__ int tsum[256];
    const int tid = threadIdx.x;
    const int base = blockIdx.x * SCAN_E + tid * 8;
    int c[8];
    int s = 0;
    #pragma unroll
    for (int k = 0; k < 8; ++k) {
        int idx = base + k;
        c[k] = (idx < N_NODES) ? cnt[idx] : 0;
        s += c[k];
    }
    tsum[tid] = s;
    __syncthreads();
    for (int off = 1; off < 256; off <<= 1) {
        int add = (tid >= off) ? tsum[tid - off] : 0;
        __syncthreads();
        tsum[tid] += add;
        __syncthreads();
    }
    int off0 = bsums[blockIdx.x] + tsum[tid] - s;
    #pragma unroll
    for (int k = 0; k < 8; ++k) {
        int idx = base + k;
        if (idx < N_NODES) {
            start[idx] = off0;
            inv[idx]   = 1.0f / fmaxf((float)c[k], 1.0f);
            if ((idx & 511) == 0) bcur[idx >> 9] = off0;   // bucket write cursor
            off0 += c[k];
        }
    }
}

// Phase B: block-local LDS binning -> one global atomic per (block,bucket), dense writes.
__global__ __launch_bounds__(256) void bin_fill_kernel(const int* __restrict__ src,
                                                       const int* __restrict__ dst,
                                                       int* __restrict__ bcur,
                                                       int2* __restrict__ pairs) {
    __shared__ int2 ep[FILL_CHUNK];      // 64 KB edge stage
    __shared__ int  hist[NBUCKET];       // 3.9 KB: count -> base cursor
    const int t  = threadIdx.x;
    const int e0 = blockIdx.x * FILL_CHUNK;
    const int n  = min(FILL_CHUNK, N_EDGES - e0);

    for (int i = t; i < NBUCKET; i += 256) hist[i] = 0;
    __syncthreads();
    for (int i = t; i < n; i += 256) {
        int s = src[e0 + i], d = dst[e0 + i];
        ep[i] = make_int2(s, d);
        atomicAdd(&hist[d >> 9], 1);
    }
    __syncthreads();
    for (int i = t; i < NBUCKET; i += 256) {
        int c = hist[i];
        hist[i] = c ? atomicAdd(&bcur[i], c) : 0;   // reserve dense region
    }
    __syncthreads();
    for (int i = t; i < n; i += 256) {
        int2 p = ep[i];
        int pos = atomicAdd(&hist[p.y >> 9], 1);    // LDS cursor
        pairs[pos] = p;
    }
}

// Phase C: block = bucket; per-node cursors in LDS; srcs writes land in an 8KB window.
__global__ __launch_bounds__(256) void bucket_scatter_kernel(const int* __restrict__ start,
                                                             const int2* __restrict__ pairs,
                                                             int* __restrict__ srcs) {
    __shared__ int cur[512];
    const int b   = blockIdx.x;
    const int nb0 = b << 9;
    const int nend = min(nb0 + 512, N_NODES);
    const int t = threadIdx.x;
    for (int i = t; i < nend - nb0; i += 256) cur[i] = start[nb0 + i];
    __syncthreads();
    const int ebeg = start[nb0];
    const int eend = (nend < N_NODES) ? start[nend] : N_EDGES;
    for (int i = ebeg + t; i < eend; i += 256) {
        int2 p = pairs[i];
        int pos = atomicAdd(&cur[p.y - nb0], 1);    // LDS atomic
        srcs[pos] = p.x;
    }
}

// ---------------- gather: ns_bf[n] = bf16(mean nbr h_bf), 16 lanes/node, unroll-4 ----
__global__ __launch_bounds__(256) void gather_kernel(const int* __restrict__ start,
                                                     const int* __restrict__ cnt,
                                                     const int* __restrict__ srcs,
                                                     const float* __restrict__ inv,
                                                     const unsigned short* __restrict__ hb,
                                                     unsigned short* __restrict__ nsb) {
    const int idx  = blockIdx.x * 256 + threadIdx.x;
    const int node = idx >> 4;
    if (node >= N_NODES) return;
    const int f = (idx & 15) * 8;
    const int st = start[node];
    const int c  = cnt[node];
    float a[8];
    #pragma unroll
    for (int i = 0; i < 8; ++i) a[i] = 0.f;
    int j = 0;
    for (; j + 4 <= c; j += 4) {           // 4 outstanding 16B loads
        const int s0 = srcs[st + j + 0];
        const int s1 = srcs[st + j + 1];
        const int s2 = srcs[st + j + 2];
        const int s3 = srcs[st + j + 3];
        const short8v v0 = *(const short8v*)(hb + (size_t)s0 * H + f);
        const short8v v1 = *(const short8v*)(hb + (size_t)s1 * H + f);
        const short8v v2 = *(const short8v*)(hb + (size_t)s2 * H + f);
        const short8v v3 = *(const short8v*)(hb + (size_t)s3 * H + f);
        #pragma unroll
        for (int i = 0; i < 8; ++i)
            a[i] += (bf2f((unsigned short)v0[i]) + bf2f((unsigned short)v1[i]))
                  + (bf2f((unsigned short)v2[i]) + bf2f((unsigned short)v3[i]));
    }
    if (j + 2 <= c) {
        const int s0 = srcs[st + j + 0];
        const int s1 = srcs[st + j + 1];
        const short8v v0 = *(const short8v*)(hb + (size_t)s0 * H + f);
        const short8v v1 = *(const short8v*)(hb + (size_t)s1 * H + f);
        #pragma unroll
        for (int i = 0; i < 8; ++i)
            a[i] += bf2f((unsigned short)v0[i]) + bf2f((unsigned short)v1[i]);
        j += 2;
    }
    if (j < c) {
        const int s0 = srcs[st + j];
        const short8v v0 = *(const short8v*)(hb + (size_t)s0 * H + f);
        #pragma unroll
        for (int i = 0; i < 8; ++i) a[i] += bf2f((unsigned short)v0[i]);
    }
    const float iv = inv[node];
    short8v o;
    #pragma unroll
    for (int i = 0; i < 8; ++i) o[i] = (short)f2bf(a[i] * iv);
    *(short8v*)(nsb + (size_t)node * H + f) = o;
}

// ---------------- combine: out = relu([h|ns] @ [Ws;Wn] + b), K=256 MFMA ---------------
// bf16 layers: direct scalar stores (measured ~4.8 TB/s effective, near-roof).
// fp32 last layer: wave-private LDS transpose -> float4 stores (was 2.7 TB/s scalar).
__global__ __launch_bounds__(512, 2) void combine_mfma(const short* __restrict__ Wfrag,
                                                       const float* __restrict__ bias,
                                                       const unsigned short* __restrict__ hb,
                                                       const unsigned short* __restrict__ nsb,
                                                       unsigned short* __restrict__ outb,
                                                       float* __restrict__ outf,
                                                       int last) {
    __shared__ __align__(16) float eplds[8][16 * 68];   // per-wave [16][68] f32 (fp32 path)
    const int wave = threadIdx.x >> 6;
    const int lane = threadIdx.x & 63;
    const int wc   = wave & 1;
    float* myl = &eplds[wave][0];

    short8v Bf[4][8];
    #pragma unroll
    for (int ct = 0; ct < 4; ++ct)
        #pragma unroll
        for (int ks = 0; ks < 8; ++ks)
            Bf[ct][ks] = ((const short8v*)Wfrag)[(size_t)(((wc * 4 + ct) * 8 + ks) * 64 + lane)];

    float bs[4];
    #pragma unroll
    for (int ct = 0; ct < 4; ++ct) bs[ct] = bias[wc * 64 + ct * 16 + (lane & 15)];

    const int ntasks = (N_NODES / 16) * 2;   // 62500
    for (int task = blockIdx.x * 8 + wave; task < ntasks; task += gridDim.x * 8) {
        const int r0 = (task >> 1) * 16;
        const unsigned short* arow = hb  + (size_t)(r0 + (lane & 15)) * H + (lane >> 4) * 8;
        const unsigned short* nrow = nsb + (size_t)(r0 + (lane & 15)) * H + (lane >> 4) * 8;
        short8v Af[8];
        #pragma unroll
        for (int ks = 0; ks < 4; ++ks) Af[ks]     = *(const short8v*)(arow + ks * 32);
        #pragma unroll
        for (int ks = 0; ks < 4; ++ks) Af[4 + ks] = *(const short8v*)(nrow + ks * 32);

        f32x4 acc[4];
        #pragma unroll
        for (int ct = 0; ct < 4; ++ct) acc[ct] = (f32x4){0.f, 0.f, 0.f, 0.f};
        #pragma unroll
        for (int ks = 0; ks < 8; ++ks)
            #pragma unroll
            for (int ct = 0; ct < 4; ++ct)
                acc[ct] = __builtin_amdgcn_mfma_f32_16x16x32_bf16(Af[ks], Bf[ct][ks], acc[ct], 0, 0, 0);

        if (!last) {
            #pragma unroll
            for (int ct = 0; ct < 4; ++ct) {
                const int col = wc * 64 + ct * 16 + (lane & 15);
                #pragma unroll
                for (int q = 0; q < 4; ++q) {
                    float v = fmaxf(acc[ct][q] + bs[ct], 0.f);
                    outb[(size_t)(r0 + (lane >> 4) * 4 + q) * H + col] = f2bf(v);
                }
            }
        } else {
            #pragma unroll
            for (int ct = 0; ct < 4; ++ct)
                #pragma unroll
                for (int q = 0; q < 4; ++q)
                    myl[((lane >> 4) * 4 + q) * 68 + ct * 16 + (lane & 15)] =
                        fmaxf(acc[ct][q] + bs[ct], 0.f);
            asm volatile("s_waitcnt lgkmcnt(0)" ::: "memory");
            __builtin_amdgcn_sched_barrier(0);
            #pragma unroll
            for (int i = 0; i < 4; ++i) {
                const int g = i * 64 + lane;               // 256 float4 in tile
                const int rw = g >> 4, seg = g & 15;
                float4 val = *(const float4*)(myl + rw * 68 + seg * 4);
                *(float4*)(outf + (size_t)(r0 + rw) * H + wc * 64 + seg * 4) = val;
            }
            asm volatile("" ::: "memory");                 // reads done before next overwrite
        }
    }
}

// ---------------- launch ----------------
extern "C" void kernel_launch(void* const* d_in, const int* in_sizes, int n_in,
                              void* d_out, int out_size, void* d_ws, size_t ws_size,
                              hipStream_t stream) {
    const float* x        = (const float*)d_in[0];
    const int*   edge_src = (const int*)d_in[1];
    const int*   edge_dst = (const int*)d_in[2];
    const float* W_in     = (const float*)d_in[3];
    const float* b_in     = (const float*)d_in[4];
    const float* W_self   = (const float*)d_in[5];
    const float* W_neigh  = (const float*)d_in[6];
    const float* b_layers = (const float*)d_in[7];

    // ws layout (~272.4 MB, all 16B-aligned)
    unsigned short* h0  = (unsigned short*)d_ws;               // 128 MB
    unsigned short* nsb = h0 + (size_t)N_NODES * H;            // 128 MB (pairs alias pre-gather)
    int*   cnt    = (int*)(nsb + (size_t)N_NODES * H);         // 2 MB
    int*   start  = cnt + N_NODES;                             // 2 MB
    float* inv    = (float*)(start + N_NODES);                 // 2 MB
    int*   srcs   = (int*)(inv + N_NODES);                     // 8 MB
    int*   bsums  = srcs + N_EDGES;                            // 1 KB
    short* Wfrag  = (short*)(bsums + 256);                     // 192 KB  [3][64][64][8]
    short* WfragIn = Wfrag + (size_t)NLAYERS * 64 * 64 * 8;    // 32 KB   [32][64][8]
    int*   bcur   = (int*)(WfragIn + 32 * 64 * 8);             // 4 KB (977 used)
    int2*  pairs  = (int2*)nsb;                                // 16 MB, dead before gather
    // h1 (bf16) lives in d_out's lower 128 MB until the final fp32 write
    unsigned short* h1 = (unsigned short*)d_out;

    prep_w_kernel<<<(NLAYERS * 64 * 64 + 32 * 64 + 255) / 256, 256, 0, stream>>>(
        W_self, W_neigh, W_in, Wfrag, WfragIn);

    // CSR build (edge_dst static): hist -> scan -> LDS-binned two-phase fill
    zero_int_kernel<<<(N_NODES + 255) / 256, 256, 0, stream>>>(cnt, N_NODES);
    hist_kernel<<<(N_EDGES + 255) / 256, 256, 0, stream>>>(edge_dst, cnt);
    scan_reduce_kernel<<<NB_SCAN, 256, 0, stream>>>(cnt, bsums);
    scan_bsums_kernel<<<1, 256, 0, stream>>>(bsums);
    scan_final_kernel<<<NB_SCAN, 256, 0, stream>>>(cnt, bsums, start, inv, bcur);
    bin_fill_kernel<<<NB_FILL, 256, 0, stream>>>(edge_src, edge_dst, bcur, pairs);
    bucket_scatter_kernel<<<NBUCKET, 256, 0, stream>>>(start, pairs, srcs);

    // input projection (MFMA, fused fp32->bf16 convert via dwordx4, fast-tanh epilogue)
    proj_mfma<<<1024, 512, 0, stream>>>(WfragIn, b_in, x, h0);

    const int gather_grid = (N_NODES * 16 + 255) / 256;
    // L0: h0 -> h1 ; L1: h1 -> h0 ; L2: h0 -> fp32 d_out
    gather_kernel<<<gather_grid, 256, 0, stream>>>(start, cnt, srcs, inv, h0, nsb);
    combine_mfma<<<1024, 512, 0, stream>>>(Wfrag + 0 * 64 * 64 * 8, b_layers + 0 * H,
                                           h0, nsb, h1, nullptr, 0);
    gather_kernel<<<gather_grid, 256, 0, stream>>>(start, cnt, srcs, inv, h1, nsb);
    combine_mfma<<<1024, 512, 0, stream>>>(Wfrag + 1 * 64 * 64 * 8, b_layers + 1 * H,
                                           h1, nsb, h0, nullptr, 0);
    gather_kernel<<<gather_grid, 256, 0, stream>>>(start, cnt, srcs, inv, h0, nsb);
    combine_mfma<<<1024, 512, 0, stream>>>(Wfrag + 2 * 64 * 64 * 8, b_layers + 2 * H,
                                           h0, nsb, nullptr, (float*)d_out, 1);
}